// Round 1
// baseline (297.992 us; speedup 1.0000x reference)
//
#include <hip/hip_runtime.h>

// Masked dot-product attention, fp32 flash-style.
// B=8, LQ=LK=2048, D=64. scores = QK^T/8, mask kv>=valid_len -> -1e6, softmax, PV.
// Round 0: fp32 VALU baseline (no fp32 MFMA on CDNA4). Online softmax + exact
// skipping of fully-masked K-tiles (exp(-1e6 - m) == 0 in fp32).

constexpr int NB   = 8;
constexpr int SLQ  = 2048;
constexpr int SLK  = 2048;
constexpr int DD   = 64;
constexpr int BQ   = 32;   // q rows per block
constexpr int BK   = 64;   // keys per tile
constexpr int NT   = 128;  // threads per block
constexpr int LSTR = 68;   // padded LDS stride in floats (breaks stride-64 bank pattern)

__launch_bounds__(NT, 2)
__global__ void attn_fwd_fp32(const float* __restrict__ Q,
                              const float* __restrict__ K,
                              const float* __restrict__ V,
                              const int* __restrict__ vlens,
                              float* __restrict__ Out) {
  __shared__ float Qs[BQ * LSTR];
  __shared__ float Ks[BK * LSTR];
  __shared__ float Vs[BK * LSTR];
  __shared__ float Ps[BQ * LSTR];

  const int t  = threadIdx.x;
  const int tr = t >> 4;   // 0..7  : row group
  const int tc = t & 15;   // 0..15 : col group
  const int b  = blockIdx.x & 7;   // interleave batches for load balance
  const int qt = blockIdx.x >> 3;  // 0..63
  const int q0 = qt * BQ;

  const int vlen = vlens[b];

  const float* Qg = Q + ((size_t)b * SLQ + q0) * DD;
  const float* Kg = K + (size_t)b * SLK * DD;
  const float* Vg = V + (size_t)b * SLK * DD;

  // ---- stage Q tile (32x64) once ----
#pragma unroll
  for (int it = 0; it < (BQ * DD / 4) / NT; ++it) {  // 4 iters
    int idx = it * NT + t;
    int r = idx >> 4, c = (idx & 15) << 2;
    *(float4*)&Qs[r * LSTR + c] = *(const float4*)(Qg + r * DD + c);
  }

  float  m[4], l[4];
  float4 oacc[4];  // rows tr+8i, dims tc*4..tc*4+3
#pragma unroll
  for (int i = 0; i < 4; ++i) {
    m[i] = -1e30f;
    l[i] = 0.f;
    oacc[i] = make_float4(0.f, 0.f, 0.f, 0.f);
  }

  // tiles fully past valid_len contribute exactly zero -> skip them
  const int nkt = min((vlen + BK - 1) / BK, SLK / BK);

  for (int kt = 0; kt < nkt; ++kt) {
    __syncthreads();  // previous phase-2 finished with Vs/Ps
    // ---- stage K,V tiles (64x64 each) ----
#pragma unroll
    for (int it = 0; it < (BK * DD / 4) / NT; ++it) {  // 8 iters
      int idx = it * NT + t;
      int r = idx >> 4, c = (idx & 15) << 2;
      size_t g = (size_t)(kt * BK + r) * DD + c;
      *(float4*)&Ks[r * LSTR + c] = *(const float4*)(Kg + g);
      *(float4*)&Vs[r * LSTR + c] = *(const float4*)(Vg + g);
    }
    __syncthreads();

    // ---- phase 1: S[32][64] = Q K^T ; thread owns rows tr+8i, cols tc+16j ----
    float s[4][4];
#pragma unroll
    for (int i = 0; i < 4; ++i)
#pragma unroll
      for (int j = 0; j < 4; ++j) s[i][j] = 0.f;

#pragma unroll 4
    for (int d0 = 0; d0 < DD; d0 += 4) {
      float4 a[4], bb[4];
#pragma unroll
      for (int i = 0; i < 4; ++i) a[i] = *(const float4*)&Qs[(tr + 8 * i) * LSTR + d0];
#pragma unroll
      for (int j = 0; j < 4; ++j) bb[j] = *(const float4*)&Ks[(tc + 16 * j) * LSTR + d0];
#pragma unroll
      for (int i = 0; i < 4; ++i)
#pragma unroll
        for (int j = 0; j < 4; ++j) {
          s[i][j] += a[i].x * bb[j].x;
          s[i][j] += a[i].y * bb[j].y;
          s[i][j] += a[i].z * bb[j].z;
          s[i][j] += a[i].w * bb[j].w;
        }
    }

    // ---- mask + scale (reference: scale first, masked -> exactly -1e6) ----
    const int kbase = kt * BK;
    bool valid[4];
#pragma unroll
    for (int j = 0; j < 4; ++j) valid[j] = (kbase + tc + 16 * j) < vlen;
#pragma unroll
    for (int i = 0; i < 4; ++i)
#pragma unroll
      for (int j = 0; j < 4; ++j)
        s[i][j] = valid[j] ? s[i][j] * 0.125f : -1e6f;

    // ---- online softmax: row stats over 16-lane groups ----
    float mnew[4], corr[4];
#pragma unroll
    for (int i = 0; i < 4; ++i) {
      float mx = fmaxf(fmaxf(s[i][0], s[i][1]), fmaxf(s[i][2], s[i][3]));
#pragma unroll
      for (int w = 1; w < 16; w <<= 1) mx = fmaxf(mx, __shfl_xor(mx, w));
      mnew[i] = fmaxf(m[i], mx);
      corr[i] = __expf(m[i] - mnew[i]);
    }

    float p[4][4];
#pragma unroll
    for (int i = 0; i < 4; ++i) {
      float rs = 0.f;
#pragma unroll
      for (int j = 0; j < 4; ++j) {
        p[i][j] = __expf(s[i][j] - mnew[i]);  // masked: exp(-1e6 - m) == 0
        rs += p[i][j];
      }
#pragma unroll
      for (int w = 1; w < 16; w <<= 1) rs += __shfl_xor(rs, w);
      l[i] = l[i] * corr[i] + rs;
      m[i] = mnew[i];
      oacc[i].x *= corr[i]; oacc[i].y *= corr[i];
      oacc[i].z *= corr[i]; oacc[i].w *= corr[i];
    }

    // ---- write P tile to LDS ----
#pragma unroll
    for (int i = 0; i < 4; ++i)
#pragma unroll
      for (int j = 0; j < 4; ++j)
        Ps[(tr + 8 * i) * LSTR + tc + 16 * j] = p[i][j];

    __syncthreads();

    // ---- phase 2: O[32][64] += P V ; thread owns rows tr+8i, dims tc*4 ----
#pragma unroll 4
    for (int k0 = 0; k0 < BK; k0 += 4) {
      float4 pp[4], vv[4];
#pragma unroll
      for (int i = 0; i < 4; ++i) pp[i] = *(const float4*)&Ps[(tr + 8 * i) * LSTR + k0];
#pragma unroll
      for (int q = 0; q < 4; ++q) vv[q] = *(const float4*)&Vs[(k0 + q) * LSTR + (tc << 2)];
#pragma unroll
      for (int i = 0; i < 4; ++i) {
        oacc[i].x += pp[i].x * vv[0].x + pp[i].y * vv[1].x + pp[i].z * vv[2].x + pp[i].w * vv[3].x;
        oacc[i].y += pp[i].x * vv[0].y + pp[i].y * vv[1].y + pp[i].z * vv[2].y + pp[i].w * vv[3].y;
        oacc[i].z += pp[i].x * vv[0].z + pp[i].y * vv[1].z + pp[i].z * vv[2].z + pp[i].w * vv[3].z;
        oacc[i].w += pp[i].x * vv[0].w + pp[i].y * vv[1].w + pp[i].z * vv[2].w + pp[i].w * vv[3].w;
      }
    }
  }

  // ---- epilogue: normalize and store ----
#pragma unroll
  for (int i = 0; i < 4; ++i) {
    float inv = 1.0f / l[i];  // l >= 1 (vlen >= 1 -> at least one p == 1)
    float4 o = oacc[i];
    o.x *= inv; o.y *= inv; o.z *= inv; o.w *= inv;
    int r = tr + 8 * i;
    *(float4*)(Out + ((size_t)b * SLQ + q0 + r) * DD + (tc << 2)) = o;
  }
}

extern "C" void kernel_launch(void* const* d_in, const int* in_sizes, int n_in,
                              void* d_out, int out_size, void* d_ws, size_t ws_size,
                              hipStream_t stream) {
  const float* Q  = (const float*)d_in[0];
  const float* K  = (const float*)d_in[1];
  const float* V  = (const float*)d_in[2];
  const int*   vl = (const int*)d_in[3];
  float* out = (float*)d_out;

  dim3 grid(NB * (SLQ / BQ));  // 512 blocks
  dim3 block(NT);
  hipLaunchKernelGGL(attn_fwd_fp32, grid, block, 0, stream, Q, K, V, vl, out);
}

// Round 2
// 131.653 us; speedup vs baseline: 2.2635x; 2.2635x over previous
//
#include <hip/hip_runtime.h>

// Masked dot-product attention. B=8, LQ=LK=2048, D=64, fp32 in/out.
// scores = QK^T/8; key positions >= valid_len[b] -> -1e6; softmax; @V.
//
// Round 2: MFMA path. CDNA4 has no fp32-input MFMA, so emulate fp32 with
// bf16x3 splits (x = hi + lo; x*y ~= hi*hi + lo*hi + hi*lo, rel err ~2^-16).
// Pre-pass converts Q,K -> bf16 hi/lo planes and V -> TRANSPOSED Vt[b][d][key]
// hi/lo planes in d_ws, so every MFMA fragment is a contiguous 16B load.
// mfma_f32_16x16x32_bf16 layouts (learn_hip m89-verified):
//   A: row = lane&15, k = 8*(lane>>4)+j (contiguous)    B: col = lane&15, same k
//   C/D: col = lane&15, row = (lane>>4)*4 + reg

typedef float f32x4 __attribute__((ext_vector_type(4)));
typedef short bf16x8 __attribute__((ext_vector_type(8)));
typedef unsigned short u16;
typedef u16 u16x8 __attribute__((ext_vector_type(8)));

constexpr int NB = 8, L = 2048, D = 64;
constexpr int BQ = 32;  // q rows per block (per wave; waves split keys 4-way)
constexpr int BK = 32;  // keys per tile

__device__ __forceinline__ u16 f2bf(float x) {  // fp32 -> bf16 RNE
  unsigned u = __float_as_uint(x);
  return (u16)((u + 0x7fffu + ((u >> 16) & 1u)) >> 16);
}
__device__ __forceinline__ float bf2f(u16 h) {
  return __uint_as_float(((unsigned)h) << 16);
}

// ---------------- pre-pass 1: elementwise fp32 -> bf16 hi/lo ----------------
__global__ void conv_hilo(const float* __restrict__ src, u16* __restrict__ hi,
                          u16* __restrict__ lo, int n8) {
  int i = blockIdx.x * blockDim.x + threadIdx.x;
  if (i >= n8) return;
  const float4* s4 = (const float4*)src;
  float4 a = s4[2 * i], b = s4[2 * i + 1];
  float v[8] = {a.x, a.y, a.z, a.w, b.x, b.y, b.z, b.w};
  u16x8 h, l;
#pragma unroll
  for (int j = 0; j < 8; ++j) {
    h[j] = f2bf(v[j]);
    l[j] = f2bf(v[j] - bf2f(h[j]));
  }
  *(u16x8*)(hi + (size_t)i * 8) = h;
  *(u16x8*)(lo + (size_t)i * 8) = l;
}

// -------- pre-pass 2: V[b][key][d] -> Vt[b][d][key] bf16 hi/lo --------------
__global__ void conv_vt(const float* __restrict__ V, u16* __restrict__ hi,
                        u16* __restrict__ lo) {
  __shared__ float T[64][65];
  int b = blockIdx.x >> 5, kt = blockIdx.x & 31;
  int key0 = kt * 64;
  int t = threadIdx.x;
#pragma unroll
  for (int it = 0; it < 4; ++it) {
    int idx = it * 256 + t;
    int key = idx >> 4, c4 = (idx & 15) * 4;
    float4 v = *(const float4*)(V + ((size_t)(b * L + key0 + key)) * D + c4);
    T[c4 + 0][key] = v.x; T[c4 + 1][key] = v.y;
    T[c4 + 2][key] = v.z; T[c4 + 3][key] = v.w;
  }
  __syncthreads();
#pragma unroll
  for (int it = 0; it < 2; ++it) {
    int idx = it * 256 + t;
    int d = idx >> 3, ch = (idx & 7) * 8;
    u16x8 h, l;
#pragma unroll
    for (int e = 0; e < 8; ++e) {
      float x = T[d][ch + e];
      h[e] = f2bf(x);
      l[e] = f2bf(x - bf2f(h[e]));
    }
    size_t off = ((size_t)(b * D + d)) * L + key0 + ch;
    *(u16x8*)(hi + off) = h;
    *(u16x8*)(lo + off) = l;
  }
}

// ---------------------------- main attention --------------------------------
// grid 512 = 8 batches x 64 q-tiles; block 256 = 4 waves.
// wave w handles q rows [q0, q0+32) x key tiles {w, w+4, w+8, ...} (BK=32).
// Per-wave online softmax state; 4-way merge via LDS at the end.
__launch_bounds__(256, 2)
__global__ void attn_mfma(const u16* __restrict__ Qhi, const u16* __restrict__ Qlo,
                          const u16* __restrict__ Khi, const u16* __restrict__ Klo,
                          const u16* __restrict__ Vthi, const u16* __restrict__ Vtlo,
                          const int* __restrict__ vlens, float* __restrict__ Out) {
  // Ps rows padded to 40 u16 = 80B (bank-phase spread; 16B-aligned reads)
  __shared__ u16 Ps[4][2][2][16 * 40];     // [wave][rt][hi/lo][q*40+key] 20.5 KB
  __shared__ float Os[4][2][16][68];       // scaled partial O            34.8 KB
  __shared__ float MLs[4][2][2][16];       // [wave][rt][m/l][row]         1 KB

  const int t = threadIdx.x;
  const int w = t >> 6;
  const int ln = t & 63;
  const int lr = ln & 15;   // fragment col lane
  const int lg = ln >> 4;   // fragment k-group
  const int b = blockIdx.x & 7;       // batch -> XCD (round-robin dispatch)
  const int qt = blockIdx.x >> 3;
  const int q0 = qt * BQ;
  const int vlen = vlens[b];

  // Q fragments, resident: [row-tile][k-chunk], hi and lo
  bf16x8 qh[2][2], ql[2][2];
#pragma unroll
  for (int rt = 0; rt < 2; ++rt)
#pragma unroll
    for (int kc = 0; kc < 2; ++kc) {
      size_t off = ((size_t)(b * L + q0 + rt * 16 + lr)) * D + kc * 32 + lg * 8;
      qh[rt][kc] = *(const bf16x8*)(Qhi + off);
      ql[rt][kc] = *(const bf16x8*)(Qlo + off);
    }

  f32x4 O[2][4];
  float m[2][4], lsum[2][4];
#pragma unroll
  for (int rt = 0; rt < 2; ++rt) {
#pragma unroll
    for (int ct = 0; ct < 4; ++ct) O[rt][ct] = {0.f, 0.f, 0.f, 0.f};
#pragma unroll
    for (int r = 0; r < 4; ++r) { m[rt][r] = -1e30f; lsum[rt][r] = 0.f; }
  }

  for (int k0 = w * BK; k0 < vlen; k0 += 4 * BK) {
    // ---- K fragments (from L2-resident bf16 planes) ----
    bf16x8 kh[2][2], kl[2][2];
#pragma unroll
    for (int ct = 0; ct < 2; ++ct)
#pragma unroll
      for (int kc = 0; kc < 2; ++kc) {
        size_t off = ((size_t)(b * L + k0 + ct * 16 + lr)) * D + kc * 32 + lg * 8;
        kh[ct][kc] = *(const bf16x8*)(Khi + off);
        kl[ct][kc] = *(const bf16x8*)(Klo + off);
      }

    // ---- S = Q K^T (bf16x3: hh + lh + hl), 24 MFMAs ----
    f32x4 s[2][2];
#pragma unroll
    for (int rt = 0; rt < 2; ++rt)
#pragma unroll
      for (int ct = 0; ct < 2; ++ct) {
        f32x4 acc = {0.f, 0.f, 0.f, 0.f};
        acc = __builtin_amdgcn_mfma_f32_16x16x32_bf16(qh[rt][0], kh[ct][0], acc, 0, 0, 0);
        acc = __builtin_amdgcn_mfma_f32_16x16x32_bf16(qh[rt][1], kh[ct][1], acc, 0, 0, 0);
        acc = __builtin_amdgcn_mfma_f32_16x16x32_bf16(ql[rt][0], kh[ct][0], acc, 0, 0, 0);
        acc = __builtin_amdgcn_mfma_f32_16x16x32_bf16(ql[rt][1], kh[ct][1], acc, 0, 0, 0);
        acc = __builtin_amdgcn_mfma_f32_16x16x32_bf16(qh[rt][0], kl[ct][0], acc, 0, 0, 0);
        acc = __builtin_amdgcn_mfma_f32_16x16x32_bf16(qh[rt][1], kl[ct][1], acc, 0, 0, 0);
        s[rt][ct] = acc;
      }

    // ---- mask + scale + online softmax (C-layout rows; 16-lane reduce) ----
    const bool va0 = (k0 + lr) < vlen;
    const bool va1 = (k0 + 16 + lr) < vlen;
    float corr[2][4];
#pragma unroll
    for (int rt = 0; rt < 2; ++rt) {
#pragma unroll
      for (int r = 0; r < 4; ++r) {
        float x0 = va0 ? s[rt][0][r] * 0.125f : -1e6f;
        float x1 = va1 ? s[rt][1][r] * 0.125f : -1e6f;
        float mx = fmaxf(x0, x1);
        mx = fmaxf(mx, __shfl_xor(mx, 1));
        mx = fmaxf(mx, __shfl_xor(mx, 2));
        mx = fmaxf(mx, __shfl_xor(mx, 4));
        mx = fmaxf(mx, __shfl_xor(mx, 8));
        float mn = fmaxf(m[rt][r], mx);
        float c = __expf(m[rt][r] - mn);
        float p0 = __expf(x0 - mn);  // masked lanes: exp(-1e6-mn) == 0 exactly
        float p1 = __expf(x1 - mn);
        float rs = p0 + p1;
        rs += __shfl_xor(rs, 1);
        rs += __shfl_xor(rs, 2);
        rs += __shfl_xor(rs, 4);
        rs += __shfl_xor(rs, 8);
        lsum[rt][r] = lsum[rt][r] * c + rs;
        m[rt][r] = mn;
        corr[rt][r] = c;
        // P -> bf16 hi/lo into per-wave LDS (transpose to A-fragment layout)
        int qq = lg * 4 + r;
        u16 h0 = f2bf(p0);
        Ps[w][rt][0][qq * 40 + lr] = h0;
        Ps[w][rt][1][qq * 40 + lr] = f2bf(p0 - bf2f(h0));
        u16 h1 = f2bf(p1);
        Ps[w][rt][0][qq * 40 + 16 + lr] = h1;
        Ps[w][rt][1][qq * 40 + 16 + lr] = f2bf(p1 - bf2f(h1));
      }
#pragma unroll
      for (int ct = 0; ct < 4; ++ct)
#pragma unroll
        for (int r = 0; r < 4; ++r) O[rt][ct][r] *= corr[rt][r];
    }

    // ---- P A-fragments (per-wave LDS; same-wave RAW ordered by lgkmcnt) ----
    bf16x8 pa[2][2];
#pragma unroll
    for (int rt = 0; rt < 2; ++rt)
#pragma unroll
      for (int h = 0; h < 2; ++h)
        pa[rt][h] = *(const bf16x8*)&Ps[w][rt][h][lr * 40 + lg * 8];

    // ---- Vt B-fragments + PV (bf16x3), 24 MFMAs ----
    bf16x8 vh4[4], vl4[4];
#pragma unroll
    for (int ct = 0; ct < 4; ++ct) {
      size_t off = ((size_t)(b * D + ct * 16 + lr)) * L + k0 + lg * 8;
      vh4[ct] = *(const bf16x8*)(Vthi + off);
      vl4[ct] = *(const bf16x8*)(Vtlo + off);
    }
#pragma unroll
    for (int rt = 0; rt < 2; ++rt)
#pragma unroll
      for (int ct = 0; ct < 4; ++ct) {
        f32x4 acc = O[rt][ct];
        acc = __builtin_amdgcn_mfma_f32_16x16x32_bf16(pa[rt][0], vh4[ct], acc, 0, 0, 0);
        acc = __builtin_amdgcn_mfma_f32_16x16x32_bf16(pa[rt][1], vh4[ct], acc, 0, 0, 0);
        acc = __builtin_amdgcn_mfma_f32_16x16x32_bf16(pa[rt][0], vl4[ct], acc, 0, 0, 0);
        O[rt][ct] = acc;
      }
  }

  // ---- 4-way wave merge: out = sum_w e^{m_w-M} O_w / sum_w e^{m_w-M} l_w ----
  if (lr == 0) {
#pragma unroll
    for (int rt = 0; rt < 2; ++rt)
#pragma unroll
      for (int r = 0; r < 4; ++r) {
        MLs[w][rt][0][lg * 4 + r] = m[rt][r];
        MLs[w][rt][1][lg * 4 + r] = lsum[rt][r];
      }
  }
  __syncthreads();
#pragma unroll
  for (int rt = 0; rt < 2; ++rt)
#pragma unroll
    for (int r = 0; r < 4; ++r) {
      int qq = lg * 4 + r;
      float M4 = fmaxf(fmaxf(MLs[0][rt][0][qq], MLs[1][rt][0][qq]),
                       fmaxf(MLs[2][rt][0][qq], MLs[3][rt][0][qq]));
      float sc = __expf(m[rt][r] - M4);
#pragma unroll
      for (int ct = 0; ct < 4; ++ct)
        Os[w][rt][qq][ct * 16 + lr] = O[rt][ct][r] * sc;
    }
  __syncthreads();

  {
    int row = t >> 3;           // 0..31
    int rt = row >> 4, qq = row & 15;
    int d0 = (t & 7) * 8;
    float M4 = fmaxf(fmaxf(MLs[0][rt][0][qq], MLs[1][rt][0][qq]),
                     fmaxf(MLs[2][rt][0][qq], MLs[3][rt][0][qq]));
    float den = 0.f;
#pragma unroll
    for (int wv = 0; wv < 4; ++wv)
      den += __expf(MLs[wv][rt][0][qq] - M4) * MLs[wv][rt][1][qq];
    float inv = 1.0f / den;
    float o[8];
#pragma unroll
    for (int e = 0; e < 8; ++e) {
      float a = 0.f;
#pragma unroll
      for (int wv = 0; wv < 4; ++wv) a += Os[wv][rt][qq][d0 + e];
      o[e] = a * inv;
    }
    float* dst = Out + ((size_t)(b * L + q0 + row)) * D + d0;
    *(float4*)dst = make_float4(o[0], o[1], o[2], o[3]);
    *(float4*)(dst + 4) = make_float4(o[4], o[5], o[6], o[7]);
  }
}

// ------------- fallback (round-1 fp32 kernel) if ws too small ---------------
__launch_bounds__(128, 2)
__global__ void attn_fwd_fp32(const float* __restrict__ Q, const float* __restrict__ K,
                              const float* __restrict__ V, const int* __restrict__ vlens,
                              float* __restrict__ Out) {
  constexpr int LS = 68;
  __shared__ float Qs[32 * LS];
  __shared__ float Ks[64 * LS];
  __shared__ float Vs[64 * LS];
  __shared__ float Pss[32 * LS];
  const int t = threadIdx.x;
  const int tr = t >> 4, tc = t & 15;
  const int b = blockIdx.x & 7, qt = blockIdx.x >> 3;
  const int q0 = qt * 32;
  const int vlen = vlens[b];
  const float* Qg = Q + ((size_t)b * L + q0) * D;
  const float* Kg = K + (size_t)b * L * D;
  const float* Vg = V + (size_t)b * L * D;
#pragma unroll
  for (int it = 0; it < 4; ++it) {
    int idx = it * 128 + t;
    int r = idx >> 4, c = (idx & 15) << 2;
    *(float4*)&Qs[r * LS + c] = *(const float4*)(Qg + r * D + c);
  }
  float m[4], l[4];
  float4 oacc[4];
#pragma unroll
  for (int i = 0; i < 4; ++i) { m[i] = -1e30f; l[i] = 0.f; oacc[i] = make_float4(0, 0, 0, 0); }
  const int nkt = min((vlen + 63) / 64, L / 64);
  for (int kt = 0; kt < nkt; ++kt) {
    __syncthreads();
#pragma unroll
    for (int it = 0; it < 8; ++it) {
      int idx = it * 128 + t;
      int r = idx >> 4, c = (idx & 15) << 2;
      size_t g = (size_t)(kt * 64 + r) * D + c;
      *(float4*)&Ks[r * LS + c] = *(const float4*)(Kg + g);
      *(float4*)&Vs[r * LS + c] = *(const float4*)(Vg + g);
    }
    __syncthreads();
    float s[4][4];
#pragma unroll
    for (int i = 0; i < 4; ++i)
#pragma unroll
      for (int j = 0; j < 4; ++j) s[i][j] = 0.f;
#pragma unroll 4
    for (int d0 = 0; d0 < D; d0 += 4) {
      float4 a[4], bb[4];
#pragma unroll
      for (int i = 0; i < 4; ++i) a[i] = *(const float4*)&Qs[(tr + 8 * i) * LS + d0];
#pragma unroll
      for (int j = 0; j < 4; ++j) bb[j] = *(const float4*)&Ks[(tc + 16 * j) * LS + d0];
#pragma unroll
      for (int i = 0; i < 4; ++i)
#pragma unroll
        for (int j = 0; j < 4; ++j) {
          s[i][j] += a[i].x * bb[j].x + a[i].y * bb[j].y + a[i].z * bb[j].z + a[i].w * bb[j].w;
        }
    }
    const int kbase = kt * 64;
#pragma unroll
    for (int i = 0; i < 4; ++i)
#pragma unroll
      for (int j = 0; j < 4; ++j)
        s[i][j] = (kbase + tc + 16 * j) < vlen ? s[i][j] * 0.125f : -1e6f;
    float mnew[4], corr[4];
#pragma unroll
    for (int i = 0; i < 4; ++i) {
      float mx = fmaxf(fmaxf(s[i][0], s[i][1]), fmaxf(s[i][2], s[i][3]));
#pragma unroll
      for (int wd = 1; wd < 16; wd <<= 1) mx = fmaxf(mx, __shfl_xor(mx, wd));
      mnew[i] = fmaxf(m[i], mx);
      corr[i] = __expf(m[i] - mnew[i]);
    }
    float p[4][4];
#pragma unroll
    for (int i = 0; i < 4; ++i) {
      float rs = 0.f;
#pragma unroll
      for (int j = 0; j < 4; ++j) { p[i][j] = __expf(s[i][j] - mnew[i]); rs += p[i][j]; }
#pragma unroll
      for (int wd = 1; wd < 16; wd <<= 1) rs += __shfl_xor(rs, wd);
      l[i] = l[i] * corr[i] + rs;
      m[i] = mnew[i];
      oacc[i].x *= corr[i]; oacc[i].y *= corr[i]; oacc[i].z *= corr[i]; oacc[i].w *= corr[i];
    }
#pragma unroll
    for (int i = 0; i < 4; ++i)
#pragma unroll
      for (int j = 0; j < 4; ++j) Pss[(tr + 8 * i) * LS + tc + 16 * j] = p[i][j];
    __syncthreads();
#pragma unroll 4
    for (int k0 = 0; k0 < 64; k0 += 4) {
      float4 pp[4], vv[4];
#pragma unroll
      for (int i = 0; i < 4; ++i) pp[i] = *(const float4*)&Pss[(tr + 8 * i) * LS + k0];
#pragma unroll
      for (int q = 0; q < 4; ++q) vv[q] = *(const float4*)&Vs[(k0 + q) * LS + (tc << 2)];
#pragma unroll
      for (int i = 0; i < 4; ++i) {
        oacc[i].x += pp[i].x * vv[0].x + pp[i].y * vv[1].x + pp[i].z * vv[2].x + pp[i].w * vv[3].x;
        oacc[i].y += pp[i].x * vv[0].y + pp[i].y * vv[1].y + pp[i].z * vv[2].y + pp[i].w * vv[3].y;
        oacc[i].z += pp[i].x * vv[0].z + pp[i].y * vv[1].z + pp[i].z * vv[2].z + pp[i].w * vv[3].z;
        oacc[i].w += pp[i].x * vv[0].w + pp[i].y * vv[1].w + pp[i].z * vv[2].w + pp[i].w * vv[3].w;
      }
    }
  }
#pragma unroll
  for (int i = 0; i < 4; ++i) {
    float inv = 1.0f / l[i];
    float4 o = oacc[i];
    o.x *= inv; o.y *= inv; o.z *= inv; o.w *= inv;
    *(float4*)(Out + ((size_t)b * L + q0 + tr + 8 * i) * D + (tc << 2)) = o;
  }
}

extern "C" void kernel_launch(void* const* d_in, const int* in_sizes, int n_in,
                              void* d_out, int out_size, void* d_ws, size_t ws_size,
                              hipStream_t stream) {
  const float* Q = (const float*)d_in[0];
  const float* K = (const float*)d_in[1];
  const float* V = (const float*)d_in[2];
  const int* vl = (const int*)d_in[3];
  float* out = (float*)d_out;

  const size_t plane = (size_t)NB * L * D;  // 1,048,576 elems
  if (ws_size >= plane * 2 * 6) {           // 12 MB of bf16 planes
    u16* Qhi = (u16*)d_ws;
    u16* Qlo = Qhi + plane;
    u16* Khi = Qlo + plane;
    u16* Klo = Khi + plane;
    u16* Vthi = Klo + plane;
    u16* Vtlo = Vthi + plane;
    int n8 = (int)(plane / 8);  // 131072
    hipLaunchKernelGGL(conv_hilo, dim3((n8 + 255) / 256), dim3(256), 0, stream, Q, Qhi, Qlo, n8);
    hipLaunchKernelGGL(conv_hilo, dim3((n8 + 255) / 256), dim3(256), 0, stream, K, Khi, Klo, n8);
    hipLaunchKernelGGL(conv_vt, dim3(NB * 32), dim3(256), 0, stream, V, Vthi, Vtlo);
    hipLaunchKernelGGL(attn_mfma, dim3(NB * (L / BQ)), dim3(256), 0, stream,
                       Qhi, Qlo, Khi, Klo, Vthi, Vtlo, vl, out);
  } else {
    hipLaunchKernelGGL(attn_fwd_fp32, dim3(NB * (L / 32)), dim3(128), 0, stream,
                       Q, K, V, vl, out);
  }
}